// Round 6
// baseline (126.127 us; speedup 1.0000x reference)
//
#include <hip/hip_runtime.h>
#include <hip/hip_bf16.h>

// Problem constants
static constexpr int Bn = 8, Cn = 128, Hn = 64, Wn = 64, Con = 128;
static constexpr int KKn = 9, DGn = 2, Cgn = 64;
static constexpr int HOn = 64, WOn = 64;
static constexpr int PITCH = 72;     // bf16 row pitch for s_val rows
static constexpr int OMP3 = 66;      // s_om row pitch (shorts), 64 pos + pad

typedef short short8 __attribute__((ext_vector_type(8)));
typedef float f32x4  __attribute__((ext_vector_type(4)));

__device__ __forceinline__ unsigned short f2bf(float f) {
    unsigned u = __float_as_uint(f);
    u += 0x7fff + ((u >> 16) & 1);          // round-to-nearest-even
    return (unsigned short)(u >> 16);
}
__device__ __forceinline__ float bf2f(unsigned short h) {
    return __uint_as_float(((unsigned)h) << 16);
}

// ---------------------------------------------------------------------------
// Kernel P: merged prep (unchanged, proven).
// ---------------------------------------------------------------------------
__global__ __launch_bounds__(256) void prep(const float* __restrict__ x,
                                            const float* __restrict__ w,
                                            const float* __restrict__ ow,
                                            unsigned short* __restrict__ xt,
                                            unsigned short* __restrict__ wt2,
                                            unsigned short* __restrict__ owf) {
    __shared__ unsigned short s[128 * 64];       // 16 KB [c][x]
    const int blk = blockIdx.x;
    const int t = threadIdx.x;
    if (blk < 512) {
        const int b = blk & 7, y = blk >> 3;
#pragma unroll
        for (int i = 0; i < 32; ++i) {
            int e = t + i * 256;                 // [0,8192)
            int c = e >> 6, xc = e & 63;
            s[c * 64 + xc] = f2bf(x[(((size_t)b * Cn + c) * Hn + y) * Wn + xc]);
        }
        __syncthreads();
        unsigned short* dst = xt + ((size_t)(b * 64 + y) * 64) * 128;
#pragma unroll
        for (int i = 0; i < 4; ++i) {
            int e = t + i * 256;                 // short8 id [0,1024)
            int xc = e >> 4;
            int c0 = (e & 15) * 8;
            short8 v;
#pragma unroll
            for (int j = 0; j < 8; ++j) v[j] = (short)s[(c0 + j) * 64 + xc];
            *(short8*)&dst[(size_t)e * 8] = v;
        }
    } else if (blk < 1088) {
        int e    = (blk - 512) * 256 + t;        // [0,147456)
        int j    = e & 7;
        int lane = (e >> 3) & 63;
        int tile = (e >> 9) & 7;
        int ks   = (e >> 12) & 1;
        int gk   = e >> 13;                      // 0..17
        int g = gk / 9, k = gk - g * 9;
        int oc = tile * 16 + (lane & 15);
        int c  = ks * 32 + (lane >> 4) * 8 + j;
        wt2[e] = f2bf(w[((size_t)oc * Cn + g * Cgn + c) * KKn + k]);
    } else {
        int e = (blk - 1088) * 256 + t;          // [0,36864)
        int g  = e / 18432;
        int r  = e - g * 18432;
        int ks = r >> 10;
        int r2 = r & 1023;
        int nt = r2 >> 9;
        int lane = (r2 >> 3) & 63;
        int j  = r2 & 7;
        int tap = ks >> 1, chalf = ks & 1;
        int oc_l = nt * 16 + (lane & 15);
        int c = chalf * 32 + (lane >> 4) * 8 + j;
        float v = 0.f;
        if (oc_l < 27)
            v = ow[((size_t)(g * 27 + oc_l) * Cgn + c) * KKn + tap];
        owf[e] = f2bf(v);
    }
}

// ---------------------------------------------------------------------------
// Kernel 2 (R14): LDS x-WINDOW kernel. Full-row block (M=64, 512 thr, 8 waves,
// grid 512, 1 block/CU due to 147KB LDS).
//
// Theory after 5 falsifications: the invariant wall is the corner-gather's
// scattered L2 loads — latency x per-CU outstanding-request cap (~42us floor
// regardless of schedule/occupancy/bytes). Fix: serve corners from LDS.
//   - Stage rows [max(0,ho-3), min(63,ho+3)] x full width x 128ch (<=112KB)
//     into LDS once (coalesced streaming, BW-regime).
//   - Bilinear corners for |off|<~1 land in the window -> LDS fast path.
//     Per-wave __all() test; global-load fallback for arbitrary offsets
//     (bit-identical values either way -> correctness for any input).
//   - P0's conv taps (y in {ho-2,ho,ho+2}) are provably in-window -> P0
//     A-operands also from LDS.
//   - XOR swizzle (chunk ^= x&15) makes the 256B-strided corner reads 2-way
//     (free) instead of 8-way conflicted.
// wt2 B-frags: wave wv owns oc-tile wv (R13 mapping, slice read once/block).
// Accumulation order per output (gk asc, ks asc) unchanged -> bit-identical.
// LDS: 114688 (s_xw) + 9216 (s_scr: s_om/s_val union) + 18432 (s_cw)
//      + 4608 (s_pk) = 146,944 B.
// ---------------------------------------------------------------------------
__global__ __launch_bounds__(512, 2) void dcn_fused(const unsigned short* __restrict__ xt,
                                                    const unsigned short* __restrict__ owf,
                                                    const float* __restrict__ ob,
                                                    const unsigned short* __restrict__ wt2,
                                                    float* __restrict__ out) {
    __shared__ __align__(16) unsigned short s_xw[7 * 64 * 16 * 8];   // 114688 B window
    __shared__ __align__(16) unsigned short s_scr[64 * PITCH];       // 9216 B: s_om then s_val
    __shared__ float4 s_cw[18][64];
    __shared__ int    s_pk[18][64];

    unsigned short* s_om  = s_scr;           // [54][OMP3] during P0/P1
    unsigned short* s_val = s_scr;           // [64][PITCH] during P2

    const int t  = threadIdx.x;              // [0,512)
    const int id = blockIdx.x;               // [0,512)
    const int b  = id & 7;                   // XCD-aware: batch b -> XCD b
    const int ho = id >> 3;                  // full output row

    const int lane = t & 63;
    const int wv   = t >> 6;                 // wave id 0..7
    const int lr   = lane & 15;              // MFMA row/col part
    const int lk   = (lane >> 4) * 8;        // MFMA k offset (shorts)
    const int q    = lane >> 4;              // D row quad

    const int lo = max(0, ho - 3);
    const int hi = min(Hn - 1, ho + 3);
    const int nrows = hi - lo + 1;           // <= 7

    const unsigned short* xb0 = xt + (size_t)b * (Hn * Wn * Cn);
    const short8 zz = {0, 0, 0, 0, 0, 0, 0, 0};

    // ---- S: stage x window rows [lo,hi] into LDS (swizzled chunks) ----
    for (int e = t; e < nrows * 1024; e += 512) {
        int rs  = e >> 10;                   // row slot
        int rem = e & 1023;                  // x*16 + k
        int xx  = rem >> 4;
        int k   = rem & 15;
        short8 v = *(const short8*)&xb0[(((size_t)(lo + rs) * Wn + xx) * Cn) + k * 8];
        *(short8*)&s_xw[(((rs * 64 + xx) * 16) + (k ^ (xx & 15))) * 8] = v;
    }
    __syncthreads();

    // ---- P0: offset-conv GEMM, A-operands from LDS window ----
    // 8 waves = (cg = wv>>2, rh = (wv>>1)&1, nh = wv&1); M=32 rows each.
    {
        const int cg = wv >> 2;              // conv/deform group
        const int rh = (wv >> 1) & 1;        // row half (pos base rh*32)
        const int nh = wv & 1;               // oc 16-block
        const int oc_l = nh * 16 + lr;
        float bias = (oc_l < 27) ? ob[cg * 27 + oc_l] : 0.f;
        f32x4 oacc[2];
        oacc[0] = (f32x4){bias, bias, bias, bias};
        oacc[1] = (f32x4){bias, bias, bias, bias};

        const unsigned short* wf = owf + (size_t)cg * 18432;

        for (int tap = 0; tap < 9; ++tap) {
            int ky = tap / 3, kx = tap - ky * 3;
            int y = ho - 2 + 2 * ky;
            if (y < 0 || y >= Hn) continue;  // wave-uniform skip (zero pad)
            int slot = y - lo;               // y in [lo,hi] guaranteed
#pragma unroll
            for (int ch = 0; ch < 2; ++ch) {
                int kssl = tap * 2 + ch;
                short8 bv = *(const short8*)&wf[(size_t)kssl * 1024 + nh * 512 + lane * 8];
#pragma unroll
                for (int mt = 0; mt < 2; ++mt) {
                    int wo = rh * 32 + mt * 16 + lr;
                    int xc = wo - 2 + 2 * kx;
                    bool vx = (xc >= 0) & (xc < Wn);
                    int xcc = min(max(xc, 0), Wn - 1);
                    int kk  = (cg * 8 + ch * 4 + (lane >> 4)) ^ (xcc & 15);
                    short8 av = *(const short8*)&s_xw[(((slot * 64 + xcc) * 16) + kk) * 8];
                    av = vx ? av : zz;
                    oacc[mt] = __builtin_amdgcn_mfma_f32_16x16x32_bf16(av, bv, oacc[mt], 0, 0, 0);
                }
            }
        }
        if (oc_l < 27) {
            int c54 = cg * 27 + oc_l;
#pragma unroll
            for (int mt = 0; mt < 2; ++mt)
#pragma unroll
                for (int r = 0; r < 4; ++r)
                    s_om[c54 * OMP3 + rh * 32 + mt * 16 + q * 4 + r] = f2bf(oacc[mt][r]);
        }
    }
    __syncthreads();

    // ---- P1: sampling params for all (gk, pos) of this row ----
    for (int e = t; e < 18 * 64; e += 512) {
        int pos = e & 63;
        int wo  = pos;
        int gk  = e >> 6;
        int g  = gk / 9, k = gk - g * 9;
        int ky = k / 3,  kx = k - ky * 3;
        float offy = bf2f(s_om[(g * 18 + k * 2 + 0) * OMP3 + pos]);
        float offx = bf2f(s_om[(g * 18 + k * 2 + 1) * OMP3 + pos]);
        float mk   = bf2f(s_om[(36 + g * 9 + k) * OMP3 + pos]);
        mk = 2.0f / (1.0f + __expf(-mk));

        float py = offy + (float)(ky * 2 + ho - 2);
        float px = offx + (float)(kx * 2 + wo - 2);
        float fy = floorf(py), fx = floorf(px);
        int   y0 = (int)fy,    x0 = (int)fx;
        float wy = py - fy,    wx = px - fx;

        bool vy0 = (y0 >= 0) & (y0 < Hn);
        bool vy1 = (y0 + 1 >= 0) & (y0 + 1 < Hn);
        bool vx0 = (x0 >= 0) & (x0 < Wn);
        bool vx1 = (x0 + 1 >= 0) & (x0 + 1 < Wn);
        float4 cw;
        cw.x = (vy0 & vx0) ? (1.f - wy) * (1.f - wx) * mk : 0.f;
        cw.y = (vy0 & vx1) ? (1.f - wy) * wx * mk : 0.f;
        cw.z = (vy1 & vx0) ? wy * (1.f - wx) * mk : 0.f;
        cw.w = (vy1 & vx1) ? wy * wx * mk : 0.f;

        int y0c = min(max(y0, 0), Hn - 1);
        int y1c = min(max(y0 + 1, 0), Hn - 1);
        int x0c = min(max(x0, 0), Wn - 1);
        int x1c = min(max(x0 + 1, 0), Wn - 1);
        s_cw[gk][pos] = cw;
        s_pk[gk][pos] = y0c | (y1c << 8) | (x0c << 16) | (x1c << 24);
    }
    __syncthreads();   // also fences s_om -> s_val reuse

    // ---- P2: gather (LDS window) + MFMA loop ----
    const int pos = t >> 3;                  // gather: position 0..63
    const int cq  = (t & 7) * 8;             // gather: 8-ch chunk (group-local)

    f32x4 acc[4];                            // rows mt*16; oc tile = wv
#pragma unroll
    for (int mt = 0; mt < 4; ++mt) acc[mt] = (f32x4){0.f, 0.f, 0.f, 0.f};

    for (int gk = 0; gk < 18; ++gk) {
        // ---- gather: 4 corners x 8 channels ----
        {
            const int g = (gk >= 9) ? 1 : 0;
            float4 cw = s_cw[gk][pos];
            int pk  = s_pk[gk][pos];
            int y0c = pk & 255, y1c = (pk >> 8) & 255;
            int x0c = (pk >> 16) & 255, x1c = (pk >> 24) & 255;

            short8 a00, a01, a10, a11;
            bool ok = (y0c >= lo) & (y1c <= hi) & (y1c >= lo) & (y0c <= hi);
            if (__all(ok)) {
                // fast path: all corners in the staged window (swizzled LDS)
                const int kg = g * 8 + (t & 7);
                a00 = *(const short8*)&s_xw[((((y0c - lo) * 64 + x0c) * 16) + (kg ^ (x0c & 15))) * 8];
                a01 = *(const short8*)&s_xw[((((y0c - lo) * 64 + x1c) * 16) + (kg ^ (x1c & 15))) * 8];
                a10 = *(const short8*)&s_xw[((((y1c - lo) * 64 + x0c) * 16) + (kg ^ (x0c & 15))) * 8];
                a11 = *(const short8*)&s_xw[((((y1c - lo) * 64 + x1c) * 16) + (kg ^ (x1c & 15))) * 8];
            } else {
                // slow path (arbitrary offsets): original global gather
                const unsigned short* xb = xb0 + g * Cgn + cq;
                a00 = *(const short8*)&xb[((size_t)y0c * Wn + x0c) * Cn];
                a01 = *(const short8*)&xb[((size_t)y0c * Wn + x1c) * Cn];
                a10 = *(const short8*)&xb[((size_t)y1c * Wn + x0c) * Cn];
                a11 = *(const short8*)&xb[((size_t)y1c * Wn + x1c) * Cn];
            }
            short8 h0;
#pragma unroll
            for (int i = 0; i < 8; ++i) {
                float v = cw.x * bf2f((unsigned short)a00[i]) +
                          cw.y * bf2f((unsigned short)a01[i]) +
                          cw.z * bf2f((unsigned short)a10[i]) +
                          cw.w * bf2f((unsigned short)a11[i]);
                h0[i] = (short)f2bf(v);
            }
            *(short8*)&s_val[pos * PITCH + cq] = h0;
        }
        __syncthreads();   // s_val ready

        // ---- B frags: wave wv owns oc tile wv (slice read once/block) ----
        const unsigned short* wf = wt2 + (size_t)gk * 8192;
#pragma unroll
        for (int ks = 0; ks < 2; ++ks) {
            short8 bfr = *(const short8*)&wf[(size_t)(ks * 8 + wv) * 512 + lane * 8];
#pragma unroll
            for (int mt = 0; mt < 4; ++mt) {
                short8 af = *(const short8*)&s_val[(mt * 16 + lr) * PITCH + ks * 32 + lk];
                acc[mt] = __builtin_amdgcn_mfma_f32_16x16x32_bf16(af, bfr, acc[mt], 0, 0, 0);
            }
        }
        __syncthreads();   // s_val consumed; safe to rewrite next gk
    }

    // ---- epilogue: oc = wv*16 + lr; rows mt*16 + q*4 ----
#pragma unroll
    for (int mt = 0; mt < 4; ++mt) {
        int oc = wv * 16 + lr;
        int p0 = mt * 16 + q * 4;
        float4 v = {acc[mt][0], acc[mt][1], acc[mt][2], acc[mt][3]};
        *(float4*)&out[(((size_t)b * Con + oc) * HOn + ho) * WOn + p0] = v;
    }
}

// ---------------------------------------------------------------------------
extern "C" void kernel_launch(void* const* d_in, const int* in_sizes, int n_in,
                              void* d_out, int out_size, void* d_ws, size_t ws_size,
                              hipStream_t stream) {
    const float* x  = (const float*)d_in[0];   // [8,128,64,64]
    const float* ow = (const float*)d_in[1];   // [54,64,3,3]
    const float* ob = (const float*)d_in[2];   // [54]
    const float* w  = (const float*)d_in[3];   // [128,128,3,3]
    float* out = (float*)d_out;                // [8,128,64,64]

    // ws: x_t bf16 8,388,608 | wt2 294,912 | owf 73,728
    unsigned short* xt  = (unsigned short*)d_ws;
    unsigned short* wt2 = (unsigned short*)((char*)d_ws + 8388608);
    unsigned short* owf = (unsigned short*)((char*)d_ws + 8388608 + 294912);

    hipLaunchKernelGGL(prep, dim3(1232), dim3(256), 0, stream,
                       x, w, ow, xt, wt2, owf);
    hipLaunchKernelGGL(dcn_fused, dim3(512), dim3(512), 0, stream,
                       xt, owf, ob, wt2, out);
}

// Round 7
// 117.813 us; speedup vs baseline: 1.0706x; 1.0706x over previous
//
#include <hip/hip_runtime.h>
#include <hip/hip_bf16.h>

// Problem constants
static constexpr int Bn = 8, Cn = 128, Hn = 64, Wn = 64, Con = 128;
static constexpr int KKn = 9, DGn = 2, Cgn = 64;
static constexpr int HOn = 64, WOn = 64;
static constexpr int PITCH = 72;     // bf16 row pitch for s_val rows
static constexpr int OMP3 = 66;      // s_om row pitch (shorts), 64 pos + pad

typedef short short8 __attribute__((ext_vector_type(8)));
typedef float f32x4  __attribute__((ext_vector_type(4)));

__device__ __forceinline__ unsigned short f2bf(float f) {
    unsigned u = __float_as_uint(f);
    u += 0x7fff + ((u >> 16) & 1);          // round-to-nearest-even
    return (unsigned short)(u >> 16);
}
__device__ __forceinline__ float bf2f(unsigned short h) {
    return __uint_as_float(((unsigned)h) << 16);
}

// ---------------------------------------------------------------------------
// Kernel P: merged prep (unchanged, proven).
// ---------------------------------------------------------------------------
__global__ __launch_bounds__(256) void prep(const float* __restrict__ x,
                                            const float* __restrict__ w,
                                            const float* __restrict__ ow,
                                            unsigned short* __restrict__ xt,
                                            unsigned short* __restrict__ wt2,
                                            unsigned short* __restrict__ owf) {
    __shared__ unsigned short s[128 * 64];       // 16 KB [c][x]
    const int blk = blockIdx.x;
    const int t = threadIdx.x;
    if (blk < 512) {
        const int b = blk & 7, y = blk >> 3;
#pragma unroll
        for (int i = 0; i < 32; ++i) {
            int e = t + i * 256;                 // [0,8192)
            int c = e >> 6, xc = e & 63;
            s[c * 64 + xc] = f2bf(x[(((size_t)b * Cn + c) * Hn + y) * Wn + xc]);
        }
        __syncthreads();
        unsigned short* dst = xt + ((size_t)(b * 64 + y) * 64) * 128;
#pragma unroll
        for (int i = 0; i < 4; ++i) {
            int e = t + i * 256;                 // short8 id [0,1024)
            int xc = e >> 4;
            int c0 = (e & 15) * 8;
            short8 v;
#pragma unroll
            for (int j = 0; j < 8; ++j) v[j] = (short)s[(c0 + j) * 64 + xc];
            *(short8*)&dst[(size_t)e * 8] = v;
        }
    } else if (blk < 1088) {
        int e    = (blk - 512) * 256 + t;        // [0,147456)
        int j    = e & 7;
        int lane = (e >> 3) & 63;
        int tile = (e >> 9) & 7;
        int ks   = (e >> 12) & 1;
        int gk   = e >> 13;                      // 0..17
        int g = gk / 9, k = gk - g * 9;
        int oc = tile * 16 + (lane & 15);
        int c  = ks * 32 + (lane >> 4) * 8 + j;
        wt2[e] = f2bf(w[((size_t)oc * Cn + g * Cgn + c) * KKn + k]);
    } else {
        int e = (blk - 1088) * 256 + t;          // [0,36864)
        int g  = e / 18432;
        int r  = e - g * 18432;
        int ks = r >> 10;
        int r2 = r & 1023;
        int nt = r2 >> 9;
        int lane = (r2 >> 3) & 63;
        int j  = r2 & 7;
        int tap = ks >> 1, chalf = ks & 1;
        int oc_l = nt * 16 + (lane & 15);
        int c = chalf * 32 + (lane >> 4) * 8 + j;
        float v = 0.f;
        if (oc_l < 27)
            v = ow[((size_t)(g * 27 + oc_l) * Cgn + c) * KKn + tap];
        owf[e] = f2bf(v);
    }
}

// ---------------------------------------------------------------------------
// Kernel 2 (R15): LDS-window + WAVE-SPECIALIZED producer/consumer.
// 1024 threads (16 waves), grid 512 = (b = id&7, ho = id>>3), 1 block/CU.
//
// R14 post-mortem: the window killed the global scatter but at 8 waves/CU
// everything ran latency-exposed (occupancy 18.6%) -> slower. This round
// tests the untested quadrant: window + 16 waves/CU + overlap.
//   - waves 0-7  (producers): per gk, gather 64 pos x 8ch from the LDS
//     window + bilinear + write s_val[(gk+1)&1].
//   - waves 8-15 (consumers): per gk, one oc-16 tile each (R13 mapping):
//     2 B-frag loads + 8 ds_read + 8 MFMA on s_val[gk&1].
//   - ONE barrier per gk; dbuf s_val -> producer gk+1 runs CONCURRENTLY
//     with consumer gk on different waves (VALU || MFMA at the CU level).
// P0 (waves 0-7, A from window), P1, staging: R14-proven addressing.
// Accumulation order per output (gk asc, ks asc) unchanged -> bit-identical.
// LDS: 114688 (s_xw) + 18432 (s_val dbuf, s_om aliased) + 18432 (s_cw)
//      + 4608 (s_pk) = 156160 B -> 1 block/CU, 16 waves.
// ---------------------------------------------------------------------------
__global__ __launch_bounds__(1024, 4) void dcn_fused(const unsigned short* __restrict__ xt,
                                                     const unsigned short* __restrict__ owf,
                                                     const float* __restrict__ ob,
                                                     const unsigned short* __restrict__ wt2,
                                                     float* __restrict__ out) {
    __shared__ __align__(16) unsigned short s_xw[7 * 64 * 16 * 8];   // 114688 B window
    __shared__ __align__(16) unsigned short s_val[2][64 * PITCH];    // 18432 B dbuf
    __shared__ float4 s_cw[18][64];                                  // 18432 B
    __shared__ int    s_pk[18][64];                                  // 4608 B

    unsigned short* s_om = &s_val[0][0];     // alias: s_om (7128 B) lives pre-P2

    const int t  = threadIdx.x;              // [0,1024)
    const int id = blockIdx.x;               // [0,512)
    const int b  = id & 7;                   // XCD-aware: batch b -> XCD b
    const int ho = id >> 3;                  // full output row

    const int lane = t & 63;
    const int wv   = t >> 6;                 // wave id 0..15
    const int lr   = lane & 15;              // MFMA row/col part
    const int lk   = (lane >> 4) * 8;        // MFMA k offset (shorts)
    const int q    = lane >> 4;              // D row quad

    const int lo = max(0, ho - 3);
    const int hi = min(Hn - 1, ho + 3);
    const int nrows = hi - lo + 1;           // <= 7

    const unsigned short* xb0 = xt + (size_t)b * (Hn * Wn * Cn);
    const short8 zz = {0, 0, 0, 0, 0, 0, 0, 0};

    // ---- S: stage x window rows [lo,hi] into LDS (swizzled chunks) ----
    for (int e = t; e < nrows * 1024; e += 1024) {
        int rs  = e >> 10;                   // row slot
        int rem = e & 1023;                  // x*16 + k
        int xx  = rem >> 4;
        int k   = rem & 15;
        short8 v = *(const short8*)&xb0[(((size_t)(lo + rs) * Wn + xx) * Cn) + k * 8];
        *(short8*)&s_xw[(((rs * 64 + xx) * 16) + (k ^ (xx & 15))) * 8] = v;
    }
    __syncthreads();

    // ---- P0: offset-conv GEMM on waves 0-7, A-operands from LDS window ----
    if (wv < 8) {
        const int cg = wv >> 2;              // conv/deform group
        const int rh = (wv >> 1) & 1;        // row half (pos base rh*32)
        const int nh = wv & 1;               // oc 16-block
        const int oc_l = nh * 16 + lr;
        float bias = (oc_l < 27) ? ob[cg * 27 + oc_l] : 0.f;
        f32x4 oacc[2];
        oacc[0] = (f32x4){bias, bias, bias, bias};
        oacc[1] = (f32x4){bias, bias, bias, bias};

        const unsigned short* wf = owf + (size_t)cg * 18432;

        for (int tap = 0; tap < 9; ++tap) {
            int ky = tap / 3, kx = tap - ky * 3;
            int y = ho - 2 + 2 * ky;
            if (y < 0 || y >= Hn) continue;  // wave-uniform skip (zero pad)
            int slot = y - lo;               // y in [lo,hi] guaranteed
#pragma unroll
            for (int ch = 0; ch < 2; ++ch) {
                int kssl = tap * 2 + ch;
                short8 bv = *(const short8*)&wf[(size_t)kssl * 1024 + nh * 512 + lane * 8];
#pragma unroll
                for (int mt = 0; mt < 2; ++mt) {
                    int wo = rh * 32 + mt * 16 + lr;
                    int xc = wo - 2 + 2 * kx;
                    bool vx = (xc >= 0) & (xc < Wn);
                    int xcc = min(max(xc, 0), Wn - 1);
                    int kk  = (cg * 8 + ch * 4 + (lane >> 4)) ^ (xcc & 15);
                    short8 av = *(const short8*)&s_xw[(((slot * 64 + xcc) * 16) + kk) * 8];
                    av = vx ? av : zz;
                    oacc[mt] = __builtin_amdgcn_mfma_f32_16x16x32_bf16(av, bv, oacc[mt], 0, 0, 0);
                }
            }
        }
        if (oc_l < 27) {
            int c54 = cg * 27 + oc_l;
#pragma unroll
            for (int mt = 0; mt < 2; ++mt)
#pragma unroll
                for (int r = 0; r < 4; ++r)
                    s_om[c54 * OMP3 + rh * 32 + mt * 16 + q * 4 + r] = f2bf(oacc[mt][r]);
        }
    }
    __syncthreads();

    // ---- P1: sampling params for all (gk, pos) of this row ----
    for (int e = t; e < 18 * 64; e += 1024) {
        int pos = e & 63;
        int wo  = pos;
        int gk  = e >> 6;
        int g  = gk / 9, k = gk - g * 9;
        int ky = k / 3,  kx = k - ky * 3;
        float offy = bf2f(s_om[(g * 18 + k * 2 + 0) * OMP3 + pos]);
        float offx = bf2f(s_om[(g * 18 + k * 2 + 1) * OMP3 + pos]);
        float mk   = bf2f(s_om[(36 + g * 9 + k) * OMP3 + pos]);
        mk = 2.0f / (1.0f + __expf(-mk));

        float py = offy + (float)(ky * 2 + ho - 2);
        float px = offx + (float)(kx * 2 + wo - 2);
        float fy = floorf(py), fx = floorf(px);
        int   y0 = (int)fy,    x0 = (int)fx;
        float wy = py - fy,    wx = px - fx;

        bool vy0 = (y0 >= 0) & (y0 < Hn);
        bool vy1 = (y0 + 1 >= 0) & (y0 + 1 < Hn);
        bool vx0 = (x0 >= 0) & (x0 < Wn);
        bool vx1 = (x0 + 1 >= 0) & (x0 + 1 < Wn);
        float4 cw;
        cw.x = (vy0 & vx0) ? (1.f - wy) * (1.f - wx) * mk : 0.f;
        cw.y = (vy0 & vx1) ? (1.f - wy) * wx * mk : 0.f;
        cw.z = (vy1 & vx0) ? wy * (1.f - wx) * mk : 0.f;
        cw.w = (vy1 & vx1) ? wy * wx * mk : 0.f;

        int y0c = min(max(y0, 0), Hn - 1);
        int y1c = min(max(y0 + 1, 0), Hn - 1);
        int x0c = min(max(x0, 0), Wn - 1);
        int x1c = min(max(x0 + 1, 0), Wn - 1);
        s_cw[gk][pos] = cw;
        s_pk[gk][pos] = y0c | (y1c << 8) | (x0c << 16) | (x1c << 24);
    }
    __syncthreads();   // also fences s_om -> s_val reuse

    // ---- P2: producer/consumer gk loop, one barrier per gk ----
    // producer tile fill for gk j -> s_val[j&1]
    auto gather_tile = [&](int gkj) {
        const int pos = t >> 3;              // 0..63 (t < 512)
        const int c8  = t & 7;               // 8-ch chunk id
        const int g   = (gkj >= 9) ? 1 : 0;
        float4 cw = s_cw[gkj][pos];
        int pk  = s_pk[gkj][pos];
        int y0c = pk & 255, y1c = (pk >> 8) & 255;
        int x0c = (pk >> 16) & 255, x1c = (pk >> 24) & 255;

        short8 a00, a01, a10, a11;
        bool ok = (y0c >= lo) & (y1c <= hi);
        if (__all(ok)) {
            const int kg = g * 8 + c8;
            a00 = *(const short8*)&s_xw[((((y0c - lo) * 64 + x0c) * 16) + (kg ^ (x0c & 15))) * 8];
            a01 = *(const short8*)&s_xw[((((y0c - lo) * 64 + x1c) * 16) + (kg ^ (x1c & 15))) * 8];
            a10 = *(const short8*)&s_xw[((((y1c - lo) * 64 + x0c) * 16) + (kg ^ (x0c & 15))) * 8];
            a11 = *(const short8*)&s_xw[((((y1c - lo) * 64 + x1c) * 16) + (kg ^ (x1c & 15))) * 8];
        } else {
            const unsigned short* xb = xb0 + g * Cgn + c8 * 8;
            a00 = *(const short8*)&xb[((size_t)y0c * Wn + x0c) * Cn];
            a01 = *(const short8*)&xb[((size_t)y0c * Wn + x1c) * Cn];
            a10 = *(const short8*)&xb[((size_t)y1c * Wn + x0c) * Cn];
            a11 = *(const short8*)&xb[((size_t)y1c * Wn + x1c) * Cn];
        }
        short8 h0;
#pragma unroll
        for (int i = 0; i < 8; ++i) {
            float v = cw.x * bf2f((unsigned short)a00[i]) +
                      cw.y * bf2f((unsigned short)a01[i]) +
                      cw.z * bf2f((unsigned short)a10[i]) +
                      cw.w * bf2f((unsigned short)a11[i]);
            h0[i] = (short)f2bf(v);
        }
        *(short8*)&s_val[gkj & 1][pos * PITCH + c8 * 8] = h0;
    };

    f32x4 acc[4];
#pragma unroll
    for (int mt = 0; mt < 4; ++mt) acc[mt] = (f32x4){0.f, 0.f, 0.f, 0.f};

    if (wv < 8) gather_tile(0);              // prologue fill buf0

    for (int gk = 0; gk < 18; ++gk) {
        __syncthreads();                     // s_val[gk&1] ready for consumers
        if (wv < 8) {
            if (gk < 17) gather_tile(gk + 1);   // fill other buffer concurrently
        } else {
            const int cw8 = wv - 8;          // oc-16 tile owned by this wave
            const unsigned short* wf = wt2 + (size_t)gk * 8192;
#pragma unroll
            for (int ks = 0; ks < 2; ++ks) {
                short8 bfr = *(const short8*)&wf[(size_t)(ks * 8 + cw8) * 512 + lane * 8];
#pragma unroll
                for (int mt = 0; mt < 4; ++mt) {
                    short8 af = *(const short8*)&s_val[gk & 1][(mt * 16 + lr) * PITCH + ks * 32 + lk];
                    acc[mt] = __builtin_amdgcn_mfma_f32_16x16x32_bf16(af, bfr, acc[mt], 0, 0, 0);
                }
            }
        }
    }

    // ---- epilogue (consumers): oc = cw8*16 + lr; rows mt*16 + q*4 ----
    if (wv >= 8) {
        const int cw8 = wv - 8;
#pragma unroll
        for (int mt = 0; mt < 4; ++mt) {
            int oc = cw8 * 16 + lr;
            int p0 = mt * 16 + q * 4;
            float4 v = {acc[mt][0], acc[mt][1], acc[mt][2], acc[mt][3]};
            *(float4*)&out[(((size_t)b * Con + oc) * HOn + ho) * WOn + p0] = v;
        }
    }
}

// ---------------------------------------------------------------------------
extern "C" void kernel_launch(void* const* d_in, const int* in_sizes, int n_in,
                              void* d_out, int out_size, void* d_ws, size_t ws_size,
                              hipStream_t stream) {
    const float* x  = (const float*)d_in[0];   // [8,128,64,64]
    const float* ow = (const float*)d_in[1];   // [54,64,3,3]
    const float* ob = (const float*)d_in[2];   // [54]
    const float* w  = (const float*)d_in[3];   // [128,128,3,3]
    float* out = (float*)d_out;                // [8,128,64,64]

    // ws: x_t bf16 8,388,608 | wt2 294,912 | owf 73,728
    unsigned short* xt  = (unsigned short*)d_ws;
    unsigned short* wt2 = (unsigned short*)((char*)d_ws + 8388608);
    unsigned short* owf = (unsigned short*)((char*)d_ws + 8388608 + 294912);

    hipLaunchKernelGGL(prep, dim3(1232), dim3(256), 0, stream,
                       x, w, ow, xt, wt2, owf);
    hipLaunchKernelGGL(dcn_fused, dim3(512), dim3(1024), 0, stream,
                       xt, owf, ob, wt2, out);
}